// Round 19
// baseline (46.451 us; speedup 1.0000x reference)
//
#include <hip/hip_runtime.h>
#include <cmath>

#define NB 4
#define NT 20
#define NC 128
#define ND 64
#define TD 1280   // T*D

typedef short short8 __attribute__((ext_vector_type(8)));
typedef float f32x4 __attribute__((ext_vector_type(4)));

static __device__ __forceinline__ unsigned short f2bf(float f) {
  union { float f; unsigned int u; } v; v.f = f;
  unsigned int r = v.u + 0x7FFFu + ((v.u >> 16) & 1u);
  return (unsigned short)(r >> 16);
}

static __device__ __forceinline__ void conv16(const float* __restrict__ s,
                                              unsigned short* __restrict__ d) {
#pragma unroll
  for (int q = 0; q < 2; q++) {
    float4 f0 = *(const float4*)(s + q * 8);
    float4 f1 = *(const float4*)(s + q * 8 + 4);
    uint4 o;
    o.x = (unsigned)f2bf(f0.x) | ((unsigned)f2bf(f0.y) << 16);
    o.y = (unsigned)f2bf(f0.z) | ((unsigned)f2bf(f0.w) << 16);
    o.z = (unsigned)f2bf(f1.x) | ((unsigned)f2bf(f1.y) << 16);
    o.w = (unsigned)f2bf(f1.z) | ((unsigned)f2bf(f1.w) << 16);
    *(uint4*)(d + q * 8) = o;
  }
}

// Convert 16 f32 -> 16 bf16 stored as two XOR-swizzled 16B LDS pieces.
static __device__ __forceinline__ void conv16_lds(const float* __restrict__ s,
                                                  char* __restrict__ base,
                                                  int byte0, int swz) {
#pragma unroll
  for (int q = 0; q < 2; q++) {
    float4 f0 = *(const float4*)(s + q * 8);
    float4 f1 = *(const float4*)(s + q * 8 + 4);
    uint4 o;
    o.x = (unsigned)f2bf(f0.x) | ((unsigned)f2bf(f0.y) << 16);
    o.y = (unsigned)f2bf(f0.z) | ((unsigned)f2bf(f0.w) << 16);
    o.z = (unsigned)f2bf(f1.x) | ((unsigned)f2bf(f1.y) << 16);
    o.w = (unsigned)f2bf(f1.z) | ((unsigned)f2bf(f1.w) << 16);
    *(uint4*)(base + ((byte0 + q * 16) ^ swz)) = o;
  }
}

// ---------------------------------------------------------------------------
// D1 (k_front2): fuv GEMM with fused f32->bf16 conversion.
// NOW double-buffered A/B tiles: stage(kc+1) issued before compute(kc),
// ONE barrier per chunk (was two).  Other roles verbatim.
// ---------------------------------------------------------------------------
__global__ __launch_bounds__(128) void k_front2(
    const float* __restrict__ h, const float* __restrict__ W1,
    const float* __restrict__ W2, const float* __restrict__ W3,
    const float* __restrict__ A_m, const float* __restrict__ W_add,
    const float* __restrict__ W_mod,
    float* __restrict__ fuv,
    unsigned short* __restrict__ W2bf, unsigned short* __restrict__ W3bf,
    unsigned short* __restrict__ A_mTbf, unsigned short* __restrict__ W_addbf,
    unsigned short* __restrict__ W_modbf, unsigned short* __restrict__ hbfT) {
  __shared__ char smem[33280];
  int blk = blockIdx.x, tid = threadIdx.x;
  if (blk < 256) {
    char* atile0 = smem;               // dbuf A: [32 c][128 k] bf16, swz
    char* atile1 = smem + 8192;
    char* btile0 = smem + 16384;       // dbuf B: [16 n][128 k] bf16, swz
    char* btile1 = smem + 20480;
    int mtile = blk & 15;
    int ntile = blk >> 4;
    int lane = tid & 63;
    int w = tid >> 6;
    int lr = lane & 15, lhi = lane >> 4;
    int ac = tid >> 2;
    int akseg = (tid & 3) << 5;
    int arow_g = mtile * 32 + ac;
    int ab = arow_g >> 7, acc_c = arow_g & 127;
    int aswz = (ac & 7) << 4;
    int abase = ac * 256 + akseg * 2;
    int bn = tid >> 3;
    int bkseg = (tid & 7) << 4;
    int bn_g = ntile * 16 + bn;
    const float* bsrc_row =
        W1 + (size_t)(bn_g & 127) * (2 * TD) + (bn_g >> 7) * TD;
    int bswz = (bn & 7) << 4;
    int bbase = bn * 256 + bkseg * 2;
    int arow_l = w * 16 + lr;
    int a_rd_base = arow_l * 256;
    int a_rd_swz = (lr & 7) << 4;
    int b_rd_base = lr * 256;
    int ad0 = akseg & 63;

    // stage chunk 0 into buf0
    {
      int t5 = akseg >> 6;
      const float* src = h + (((size_t)(ab * NT + t5)) * NC + acc_c) * ND + ad0;
      conv16_lds(src, atile0, abase, aswz);
      conv16_lds(src + 16, atile0, abase + 32, aswz);
      conv16_lds(bsrc_row + bkseg, btile0, bbase, bswz);
    }
    __syncthreads();

    f32x4 acc = (f32x4){0.f, 0.f, 0.f, 0.f};
    for (int kc = 0; kc < 10; kc++) {
      // issue stage(kc+1) into the idle buffer (overlaps compute below)
      if (kc < 9) {
        int k1 = (kc + 1) * 128;
        char* an = ((kc + 1) & 1) ? atile1 : atile0;
        char* bnx = ((kc + 1) & 1) ? btile1 : btile0;
        int t5 = (k1 + akseg) >> 6;
        const float* src =
            h + (((size_t)(ab * NT + t5)) * NC + acc_c) * ND + ad0;
        conv16_lds(src, an, abase, aswz);
        conv16_lds(src + 16, an, abase + 32, aswz);
        conv16_lds(bsrc_row + k1 + bkseg, bnx, bbase, bswz);
      }
      const char* at = (kc & 1) ? atile1 : atile0;
      const char* bt = (kc & 1) ? btile1 : btile0;
#pragma unroll
      for (int ks = 0; ks < 4; ks++) {
        int koff = ks * 64 + lhi * 16;
        short8 a = *(const short8*)(at + a_rd_base + (koff ^ a_rd_swz));
        short8 bv = *(const short8*)(bt + b_rd_base + (koff ^ ((lr & 7) << 4)));
        acc = __builtin_amdgcn_mfma_f32_16x16x32_bf16(a, bv, acc, 0, 0, 0);
      }
      __syncthreads();   // stage(kc+1) writes visible; buf[kc] reads done
    }
    int m0 = mtile * 32 + w * 16 + lhi * 4;
    int n = ntile * 16 + lr;
#pragma unroll
    for (int r = 0; r < 4; r++)
      fuv[(size_t)(m0 + r) * 256 + n] = acc[r];
    return;
  }
  int cb = blk - 256;
  if (cb < 16) {
    size_t i = (size_t)cb * 2048 + tid * 16;
    conv16(W2 + i, W2bf + i);
  } else if (cb < 24) {
    size_t i = (size_t)(cb - 16) * 2048 + tid * 16;
    conv16(W3 + i, W3bf + i);
  } else if (cb < 32) {
    size_t base = (size_t)(cb - 24) * 2048 + tid * 16;
    unsigned short tmp[16];
#pragma unroll
    for (int i2 = 0; i2 < 16; i2++) {
      size_t idx = base + i2;
      int v = (int)(idx >> 7), u = (int)(idx & 127);
      tmp[i2] = f2bf(A_m[(size_t)u * 128 + v]);
    }
    *(uint4*)(A_mTbf + base) = *(uint4*)tmp;
    *(uint4*)(A_mTbf + base + 8) = *(uint4*)(tmp + 8);
  } else if (cb < 34) {
    size_t i = (size_t)(cb - 32) * 2048 + tid * 16;
    conv16(W_add + i, W_addbf + i);
  } else if (cb < 36) {
    size_t i = (size_t)(cb - 34) * 2048 + tid * 16;
    conv16(W_mod + i, W_modbf + i);
  } else {
    float (*hsl)[65] = (float (*)[65])smem;
    int bt = cb - 36;
    const float* hb = h + (size_t)bt * 8192;
    for (int i = tid; i < 8192; i += 128) hsl[i >> 6][i & 63] = hb[i];
    __syncthreads();
    unsigned short* ob = hbfT + (size_t)bt * 8192;
    for (int i = tid; i < 8192; i += 128) {
      int d = i >> 7, u = i & 127;
      ob[i] = f2bf(hsl[u][d]);
    }
  }
}

// ---------------------------------------------------------------------------
// D2: pairwise MLP -> wTbf[b][v][u].  R18 structure (256 blocks, 8 waves,
// zero-barrier main loop, W2 in LDS) + W3 FRAGMENTS IN REGISTERS
// (16 short8/lane, loaded once from L2 at entry -- same address formula as
// the proven R9 direct-read path -> bit-identical).  Removes 32 ds_reads
// per wave and the W3 LDS block.  Chunk loop fully unrolled for static
// w3f indexing + cross-chunk scheduling.  LDS: yc 32K + W2 64K = 96 KB.
// ---------------------------------------------------------------------------
__global__ __launch_bounds__(512) void k_pair(
    const float* __restrict__ fuv, const float* __restrict__ b1,
    const unsigned short* __restrict__ W2bf, const float* __restrict__ b2,
    const unsigned short* __restrict__ W3bf, const float* __restrict__ b3,
    const float* __restrict__ W4, const float* __restrict__ b4,
    const float* __restrict__ A_a, unsigned short* __restrict__ wTbf) {
  int blk = blockIdx.x;
  int b = blk >> 6;
  int u0 = (blk & 63) << 1;
  __shared__ char ycraw[8][4096];      // per-wave [32 v][64 m] bf16, swizzled
  __shared__ char w2all[65536];        // [256 m][128 k] bf16, swizzled
  int t = threadIdx.x;
  int lane = t & 63;
  int w = t >> 6;                      // 0..7
  int uw = u0 + (w >> 2);
  int lr = lane & 15;
  int lhi = lane >> 4;
  int v0w = (w & 3) * 32;
  int sw = (lr & 7) << 4;

  // ---- stage ALL W2 once (64 KB; 8 segs/wave; hides under X1 build) ----
  for (int s = w; s < 64; s += 8) {
    int o = s * 1024 + lane * 16;
    int row = o >> 8;
    int cbo = o & 255;
    const char* src = (const char*)W2bf + (size_t)row * 256 +
                      (cbo ^ ((row & 7) << 4));
    __builtin_amdgcn_global_load_lds(src, w2all + s * 1024, 16, 0, 0);
  }

  // ---- W3 fragments into registers (proven R9 direct-read formula) ----
  short8 w3f[4][2][4];                 // [chunk][ks2][n]
  {
    const unsigned short* w3base = W3bf + (size_t)lr * 256 + lhi * 8;
#pragma unroll
    for (int c = 0; c < 4; c++)
#pragma unroll
      for (int ks2 = 0; ks2 < 2; ks2++)
#pragma unroll
        for (int n = 0; n < 4; n++)
          w3f[c][ks2][n] = *(const short8*)(
              w3base + (size_t)(16 * n) * 256 + c * 64 + ks2 * 32);
  }

  // ---- X1 fragments in registers: xf[ks][vg] = relu(fu+fv+b1) bf16 ----
  short8 xf[4][2];
  {
    const float* fu_base = fuv + ((size_t)(b * NC + uw)) * 256;
#pragma unroll
    for (int ks = 0; ks < 4; ks++) {
      int k0 = ks * 32 + lhi * 8;
      float4 fua = *(const float4*)(fu_base + k0);
      float4 fub4 = *(const float4*)(fu_base + k0 + 4);
      float4 b1a = *(const float4*)(b1 + k0);
      float4 b1b = *(const float4*)(b1 + k0 + 4);
#pragma unroll
      for (int vg = 0; vg < 2; vg++) {
        int v = v0w + vg * 16 + lr;
        const float* fvr = fuv + ((size_t)(b * NC + v)) * 256 + 128 + k0;
        float4 fva = *(const float4*)(fvr);
        float4 fvb = *(const float4*)(fvr + 4);
        float e[8];
        e[0] = fua.x + fva.x + b1a.x; e[1] = fua.y + fva.y + b1a.y;
        e[2] = fua.z + fva.z + b1a.z; e[3] = fua.w + fva.w + b1a.w;
        e[4] = fub4.x + fvb.x + b1b.x; e[5] = fub4.y + fvb.y + b1b.y;
        e[6] = fub4.z + fvb.z + b1b.z; e[7] = fub4.w + fvb.w + b1b.w;
        union { unsigned int pw[4]; short8 s8; } pk;
#pragma unroll
        for (int i2 = 0; i2 < 4; i2++) {
          float lo = e[2 * i2] > 0.f ? e[2 * i2] : 0.f;
          float hi = e[2 * i2 + 1] > 0.f ? e[2 * i2 + 1] : 0.f;
          pk.pw[i2] = (unsigned int)f2bf(lo) | ((unsigned int)f2bf(hi) << 16);
        }
        xf[ks][vg] = pk.s8;
      }
    }
  }
  __syncthreads();                     // W2 stage drained (overlapped)

  char* ycb = ycraw[w];
  f32x4 zacc[2][4];
#pragma unroll
  for (int q = 0; q < 2; q++)
#pragma unroll
    for (int n = 0; n < 4; n++) zacc[q][n] = (f32x4){0.f, 0.f, 0.f, 0.f};

  // ---- main loop: zero barriers, zero staging, W3 from registers ----
#pragma unroll
  for (int c = 0; c < 4; c++) {
    int mc = c * 64;
    const char* w2base_c = w2all + mc * 256;
    f32x4 yac[4][2];
#pragma unroll
    for (int mt = 0; mt < 4; mt++) {
      yac[mt][0] = (f32x4){0.f, 0.f, 0.f, 0.f};
      yac[mt][1] = (f32x4){0.f, 0.f, 0.f, 0.f};
    }
    __builtin_amdgcn_s_setprio(1);
#pragma unroll
    for (int ks = 0; ks < 4; ks++) {
#pragma unroll
      for (int mt = 0; mt < 4; mt++) {
        int wrow = mt * 16 + lr;
        short8 wv = *(const short8*)(
            w2base_c + wrow * 256 + ((ks * 64 + lhi * 16) ^ ((wrow & 7) << 4)));
        yac[mt][0] = __builtin_amdgcn_mfma_f32_16x16x32_bf16(wv, xf[ks][0], yac[mt][0], 0, 0, 0);
        yac[mt][1] = __builtin_amdgcn_mfma_f32_16x16x32_bf16(wv, xf[ks][1], yac[mt][1], 0, 0, 0);
      }
    }
    __builtin_amdgcn_s_setprio(0);
#pragma unroll
    for (int mt = 0; mt < 4; mt++) {
      float4 b2v = *(const float4*)(b2 + mc + mt * 16 + lhi * 4);
#pragma unroll
      for (int vg = 0; vg < 2; vg++) {
        int v = vg * 16 + lr;
        float e0 = yac[mt][vg][0] + b2v.x; e0 = e0 > 0.f ? e0 : 0.f;
        float e1 = yac[mt][vg][1] + b2v.y; e1 = e1 > 0.f ? e1 : 0.f;
        float e2 = yac[mt][vg][2] + b2v.z; e2 = e2 > 0.f ? e2 : 0.f;
        float e3 = yac[mt][vg][3] + b2v.w; e3 = e3 > 0.f ? e3 : 0.f;
        uint2 pw;
        pw.x = (unsigned)f2bf(e0) | ((unsigned)f2bf(e1) << 16);
        pw.y = (unsigned)f2bf(e2) | ((unsigned)f2bf(e3) << 16);
        int byte = (v * 128 + (mt * 16 + lhi * 4) * 2) ^ ((lr & 7) << 4);
        *(uint2*)(ycb + byte) = pw;
      }
    }
    __builtin_amdgcn_s_setprio(1);
#pragma unroll
    for (int ks2 = 0; ks2 < 2; ks2++) {
      int kb = ks2 * 32 + lhi * 8;
      short8 ya0 = *(const short8*)(ycb + ((lr * 128 + kb * 2) ^ sw));
      short8 ya1 = *(const short8*)(ycb + (((16 + lr) * 128 + kb * 2) ^ sw));
#pragma unroll
      for (int n = 0; n < 4; n++) {
        zacc[0][n] = __builtin_amdgcn_mfma_f32_16x16x32_bf16(ya0, w3f[c][ks2][n], zacc[0][n], 0, 0, 0);
        zacc[1][n] = __builtin_amdgcn_mfma_f32_16x16x32_bf16(ya1, w3f[c][ks2][n], zacc[1][n], 0, 0, 0);
      }
    }
    __builtin_amdgcn_s_setprio(0);
  }

  // ---- layer3 bias/relu + layer4 dot + 16-lane butterfly + sigmoid ----
  float sp[2][4];
#pragma unroll
  for (int q = 0; q < 2; q++)
#pragma unroll
    for (int r = 0; r < 4; r++) sp[q][r] = 0.f;
#pragma unroll
  for (int n = 0; n < 4; n++) {
    int j = 16 * n + lr;
    float b3v = b3[j], w4v = W4[j];
#pragma unroll
    for (int q = 0; q < 2; q++)
#pragma unroll
      for (int r = 0; r < 4; r++) {
        float z = zacc[q][n][r] + b3v;
        z = z > 0.f ? z : 0.f;
        sp[q][r] += w4v * z;
      }
  }
#pragma unroll
  for (int mask = 1; mask <= 8; mask <<= 1)
#pragma unroll
    for (int q = 0; q < 2; q++)
#pragma unroll
      for (int r = 0; r < 4; r++)
        sp[q][r] += __shfl_xor(sp[q][r], mask, 64);
  float bb4 = b4[0];
  if (lr == 0) {
#pragma unroll
    for (int q = 0; q < 2; q++)
#pragma unroll
      for (int r = 0; r < 4; r++) {
        int v = v0w + 16 * q + lhi * 4 + r;
        float s = 1.f / (1.f + expf(-(sp[q][r] + bb4)));
        wTbf[((size_t)(b * NC + v)) * NC + uw] = f2bf(s * A_a[uw * NC + v]);
      }
  }
}

// ---------------------------------------------------------------------------
// D3: fused a/m einsums + projections + beta combine.  (verbatim R15-R18)
// ---------------------------------------------------------------------------
__global__ __launch_bounds__(128) void k_out_mfma(
    const float* __restrict__ h, const unsigned short* __restrict__ wTbf,
    const unsigned short* __restrict__ A_mTbf,
    const unsigned short* __restrict__ hbfT,
    const unsigned short* __restrict__ W_addbf,
    const unsigned short* __restrict__ W_modbf,
    const float* __restrict__ b_add, const float* __restrict__ b_mod,
    const float* __restrict__ beta1p, const float* __restrict__ beta2p,
    const float* __restrict__ beta3p, float* __restrict__ out) {
  int blk = blockIdx.x;
  int bt = blk >> 3;
  int v0 = (blk & 7) << 4;
  int b = bt / 20;
  __shared__ char apre_l[2048];
  __shared__ char mpre_l[2048];
  int t = threadIdx.x;
  int lane = t & 63;
  int w = t >> 6;
  int lr = lane & 15, lhi = lane >> 4;
  int nf0 = w * 2;

  f32x4 aacc[2], macc[2];
#pragma unroll
  for (int i = 0; i < 2; i++) {
    aacc[i] = (f32x4){0.f, 0.f, 0.f, 0.f};
    macc[i] = (f32x4){0.f, 0.f, 0.f, 0.f};
  }
  const unsigned short* wrow = wTbf + ((size_t)(b * NC + v0 + lr)) * NC + lhi * 8;
  const unsigned short* arow = A_mTbf + (size_t)(v0 + lr) * NC + lhi * 8;
  const unsigned short* hTrow = hbfT + (size_t)bt * 8192 + lhi * 8;
#pragma unroll
  for (int kb = 0; kb < 128; kb += 32) {
    short8 aw = *(const short8*)(wrow + kb);
    short8 am = *(const short8*)(arow + kb);
#pragma unroll
    for (int nfi = 0; nfi < 2; nfi++) {
      int nf = nf0 + nfi;
      short8 bv = *(const short8*)(hTrow + (size_t)(nf * 16 + lr) * NC + kb);
      aacc[nfi] = __builtin_amdgcn_mfma_f32_16x16x32_bf16(aw, bv, aacc[nfi], 0, 0, 0);
      macc[nfi] = __builtin_amdgcn_mfma_f32_16x16x32_bf16(am, bv, macc[nfi], 0, 0, 0);
    }
  }

  float hval[2][4];
  const float* hbase = h + (size_t)bt * 8192;
#pragma unroll
  for (int nfi = 0; nfi < 2; nfi++) {
    int d = (nf0 + nfi) * 16 + lr;
#pragma unroll
    for (int r = 0; r < 4; r++) {
      int vl = lhi * 4 + r;
      float hv = hbase[(size_t)(v0 + vl) * 64 + d];
      hval[nfi][r] = hv;
      int byte = (vl * 128 + d * 2) ^ ((vl & 7) << 4);
      *(unsigned short*)(apre_l + byte) = f2bf(aacc[nfi][r]);
      *(unsigned short*)(mpre_l + byte) = f2bf(macc[nfi][r] * hv);
    }
  }
  __syncthreads();

  f32x4 oa[2], om[2];
#pragma unroll
  for (int i = 0; i < 2; i++) {
    oa[i] = (f32x4){0.f, 0.f, 0.f, 0.f};
    om[i] = (f32x4){0.f, 0.f, 0.f, 0.f};
  }
  int sw = (lr & 7) << 4;
#pragma unroll
  for (int kb = 0; kb < 64; kb += 32) {
    int off0 = lr * 128 + kb * 2 + lhi * 16;
    short8 pa = *(const short8*)(apre_l + (off0 ^ sw));
    short8 pm = *(const short8*)(mpre_l + (off0 ^ sw));
#pragma unroll
    for (int nfi = 0; nfi < 2; nfi++) {
      int nf = nf0 + nfi;
      const unsigned short* wa = W_addbf + (size_t)(nf * 16 + lr) * 64 + kb + lhi * 8;
      const unsigned short* wm = W_modbf + (size_t)(nf * 16 + lr) * 64 + kb + lhi * 8;
      short8 wav = *(const short8*)wa;
      short8 wmv = *(const short8*)wm;
      oa[nfi] = __builtin_amdgcn_mfma_f32_16x16x32_bf16(pa, wav, oa[nfi], 0, 0, 0);
      om[nfi] = __builtin_amdgcn_mfma_f32_16x16x32_bf16(pm, wmv, om[nfi], 0, 0, 0);
    }
  }
  float bb1 = beta1p[0], bb2 = beta2p[0], bb3 = beta3p[0];
  float* obase = out + (size_t)bt * 8192 + (size_t)v0 * 64;
#pragma unroll
  for (int nfi = 0; nfi < 2; nfi++) {
    int d = (nf0 + nfi) * 16 + lr;
    float ba = b_add[d], bm = b_mod[d];
#pragma unroll
    for (int r = 0; r < 4; r++) {
      int vl = lhi * 4 + r;
      obase[(size_t)vl * 64 + d] =
          bb1 * hval[nfi][r] + bb2 * (oa[nfi][r] + ba) + bb3 * (om[nfi][r] + bm);
    }
  }
}

// ---------------------------------------------------------------------------
extern "C" void kernel_launch(void* const* d_in, const int* in_sizes, int n_in,
                              void* d_out, int out_size, void* d_ws, size_t ws_size,
                              hipStream_t stream) {
  const float* h     = (const float*)d_in[0];
  const float* W1    = (const float*)d_in[1];
  const float* b1    = (const float*)d_in[2];
  const float* W2    = (const float*)d_in[3];
  const float* b2    = (const float*)d_in[4];
  const float* W3    = (const float*)d_in[5];
  const float* b3    = (const float*)d_in[6];
  const float* W4    = (const float*)d_in[7];
  const float* b4    = (const float*)d_in[8];
  const float* A_a   = (const float*)d_in[9];
  const float* A_m   = (const float*)d_in[10];
  const float* W_add = (const float*)d_in[11];
  const float* b_add = (const float*)d_in[12];
  const float* W_mod = (const float*)d_in[13];
  const float* b_mod = (const float*)d_in[14];
  const float* beta1 = (const float*)d_in[15];
  const float* beta2 = (const float*)d_in[16];
  const float* beta3 = (const float*)d_in[17];
  float* out = (float*)d_out;

  char* ws = (char*)d_ws;
  float* fuv             = (float*)(ws);                         // 512 KB
  unsigned short* wTbf   = (unsigned short*)(ws + 512 * 1024);   // 128 KB
  unsigned short* A_mTbf = (unsigned short*)(ws + 640 * 1024);   // 32 KB
  unsigned short* W_addbf= (unsigned short*)(ws + 672 * 1024);   // 8 KB
  unsigned short* W_modbf= (unsigned short*)(ws + 680 * 1024);   // 8 KB
  unsigned short* W2bf   = (unsigned short*)(ws + 688 * 1024);   // 64 KB
  unsigned short* W3bf   = (unsigned short*)(ws + 752 * 1024);   // 32 KB
  unsigned short* hbfT   = (unsigned short*)(ws + 784 * 1024);   // 1280 KB

  k_front2<<<372, 128, 0, stream>>>(h, W1, W2, W3, A_m, W_add, W_mod,
                                    fuv, W2bf, W3bf, A_mTbf, W_addbf, W_modbf,
                                    hbfT);
  k_pair<<<256, 512, 0, stream>>>(fuv, b1, W2bf, b2, W3bf, b3, W4, b4, A_a, wTbf);
  k_out_mfma<<<640, 128, 0, stream>>>(h, wTbf, A_mTbf, hbfT, W_addbf, W_modbf,
                                      b_add, b_mod, beta1, beta2, beta3, out);
}

// Round 20
// 40.090 us; speedup vs baseline: 1.1587x; 1.1587x over previous
//
#include <hip/hip_runtime.h>
#include <cmath>

#define NB 4
#define NT 20
#define NC 128
#define ND 64
#define TD 1280   // T*D

typedef short short8 __attribute__((ext_vector_type(8)));
typedef float f32x4 __attribute__((ext_vector_type(4)));

static __device__ __forceinline__ unsigned short f2bf(float f) {
  union { float f; unsigned int u; } v; v.f = f;
  unsigned int r = v.u + 0x7FFFu + ((v.u >> 16) & 1u);
  return (unsigned short)(r >> 16);
}

static __device__ __forceinline__ void conv16(const float* __restrict__ s,
                                              unsigned short* __restrict__ d) {
#pragma unroll
  for (int q = 0; q < 2; q++) {
    float4 f0 = *(const float4*)(s + q * 8);
    float4 f1 = *(const float4*)(s + q * 8 + 4);
    uint4 o;
    o.x = (unsigned)f2bf(f0.x) | ((unsigned)f2bf(f0.y) << 16);
    o.y = (unsigned)f2bf(f0.z) | ((unsigned)f2bf(f0.w) << 16);
    o.z = (unsigned)f2bf(f1.x) | ((unsigned)f2bf(f1.y) << 16);
    o.w = (unsigned)f2bf(f1.z) | ((unsigned)f2bf(f1.w) << 16);
    *(uint4*)(d + q * 8) = o;
  }
}

// Convert 16 f32 -> 16 bf16 stored as two XOR-swizzled 16B LDS pieces.
static __device__ __forceinline__ void conv16_lds(const float* __restrict__ s,
                                                  char* __restrict__ base,
                                                  int byte0, int swz) {
#pragma unroll
  for (int q = 0; q < 2; q++) {
    float4 f0 = *(const float4*)(s + q * 8);
    float4 f1 = *(const float4*)(s + q * 8 + 4);
    uint4 o;
    o.x = (unsigned)f2bf(f0.x) | ((unsigned)f2bf(f0.y) << 16);
    o.y = (unsigned)f2bf(f0.z) | ((unsigned)f2bf(f0.w) << 16);
    o.z = (unsigned)f2bf(f1.x) | ((unsigned)f2bf(f1.y) << 16);
    o.w = (unsigned)f2bf(f1.z) | ((unsigned)f2bf(f1.w) << 16);
    *(uint4*)(base + ((byte0 + q * 16) ^ swz)) = o;
  }
}

// ---------------------------------------------------------------------------
// D1 (k_front2): fuv GEMM with fused f32->bf16 conversion (R16/R17 form —
// single-buffered tiles; the R19 dbuf variant regressed).
// ---------------------------------------------------------------------------
__global__ __launch_bounds__(128) void k_front2(
    const float* __restrict__ h, const float* __restrict__ W1,
    const float* __restrict__ W2, const float* __restrict__ W3,
    const float* __restrict__ A_m, const float* __restrict__ W_add,
    const float* __restrict__ W_mod,
    float* __restrict__ fuv,
    unsigned short* __restrict__ W2bf, unsigned short* __restrict__ W3bf,
    unsigned short* __restrict__ A_mTbf, unsigned short* __restrict__ W_addbf,
    unsigned short* __restrict__ W_modbf, unsigned short* __restrict__ hbfT) {
  __shared__ char smem[33280];
  int blk = blockIdx.x, tid = threadIdx.x;
  if (blk < 256) {
    char* atile = smem;
    char* btile = smem + 8192;
    int mtile = blk & 15;
    int ntile = blk >> 4;
    int lane = tid & 63;
    int w = tid >> 6;
    int lr = lane & 15, lhi = lane >> 4;
    int ac = tid >> 2;
    int akseg = (tid & 3) << 5;
    int arow_g = mtile * 32 + ac;
    int ab = arow_g >> 7, acc_c = arow_g & 127;
    int aswz = (ac & 7) << 4;
    int abase = ac * 256 + akseg * 2;
    int bn = tid >> 3;
    int bkseg = (tid & 7) << 4;
    int bn_g = ntile * 16 + bn;
    const float* bsrc_row =
        W1 + (size_t)(bn_g & 127) * (2 * TD) + (bn_g >> 7) * TD;
    int bswz = (bn & 7) << 4;
    int bbase = bn * 256 + bkseg * 2;
    int arow_l = w * 16 + lr;
    int a_rd_base = arow_l * 256;
    int a_rd_swz = (lr & 7) << 4;
    int b_rd_base = lr * 256;

    f32x4 acc = (f32x4){0.f, 0.f, 0.f, 0.f};
    for (int kc = 0; kc < 10; kc++) {
      int k0 = kc * 128;
      if (kc) __syncthreads();
      {
        int t5 = (k0 + akseg) >> 6;
        int d0 = akseg & 63;
        const float* src =
            h + (((size_t)(ab * NT + t5)) * NC + acc_c) * ND + d0;
        conv16_lds(src, atile, abase, aswz);
        conv16_lds(src + 16, atile, abase + 32, aswz);
      }
      conv16_lds(bsrc_row + k0 + bkseg, btile, bbase, bswz);
      __syncthreads();
#pragma unroll
      for (int ks = 0; ks < 4; ks++) {
        int koff = ks * 64 + lhi * 16;
        short8 a = *(const short8*)(atile + a_rd_base + (koff ^ a_rd_swz));
        short8 bv = *(const short8*)(btile + b_rd_base + (koff ^ ((lr & 7) << 4)));
        acc = __builtin_amdgcn_mfma_f32_16x16x32_bf16(a, bv, acc, 0, 0, 0);
      }
    }
    int m0 = mtile * 32 + w * 16 + lhi * 4;
    int n = ntile * 16 + lr;
#pragma unroll
    for (int r = 0; r < 4; r++)
      fuv[(size_t)(m0 + r) * 256 + n] = acc[r];
    return;
  }
  int cb = blk - 256;
  if (cb < 16) {
    size_t i = (size_t)cb * 2048 + tid * 16;
    conv16(W2 + i, W2bf + i);
  } else if (cb < 24) {
    size_t i = (size_t)(cb - 16) * 2048 + tid * 16;
    conv16(W3 + i, W3bf + i);
  } else if (cb < 32) {
    size_t base = (size_t)(cb - 24) * 2048 + tid * 16;
    unsigned short tmp[16];
#pragma unroll
    for (int i2 = 0; i2 < 16; i2++) {
      size_t idx = base + i2;
      int v = (int)(idx >> 7), u = (int)(idx & 127);
      tmp[i2] = f2bf(A_m[(size_t)u * 128 + v]);
    }
    *(uint4*)(A_mTbf + base) = *(uint4*)tmp;
    *(uint4*)(A_mTbf + base + 8) = *(uint4*)(tmp + 8);
  } else if (cb < 34) {
    size_t i = (size_t)(cb - 32) * 2048 + tid * 16;
    conv16(W_add + i, W_addbf + i);
  } else if (cb < 36) {
    size_t i = (size_t)(cb - 34) * 2048 + tid * 16;
    conv16(W_mod + i, W_modbf + i);
  } else {
    float (*hsl)[65] = (float (*)[65])smem;
    int bt = cb - 36;
    const float* hb = h + (size_t)bt * 8192;
    for (int i = tid; i < 8192; i += 128) hsl[i >> 6][i & 63] = hb[i];
    __syncthreads();
    unsigned short* ob = hbfT + (size_t)bt * 8192;
    for (int i = tid; i < 8192; i += 128) {
      int d = i >> 7, u = i & 127;
      ob[i] = f2bf(hsl[u][d]);
    }
  }
}

// ---------------------------------------------------------------------------
// D2: pairwise MLP -> wTbf[b][v][u].  R18 (best measured, 40.4 us):
// 256 blocks = (b,u-pair), 8 waves; ALL weights (96 KB) staged into LDS
// once at entry (covered by the X1 register build); ZERO-barrier main loop.
// LDS: yc 8x4K + W2 64K + W3 32K = 128 KB.
// ---------------------------------------------------------------------------
__global__ __launch_bounds__(512) void k_pair(
    const float* __restrict__ fuv, const float* __restrict__ b1,
    const unsigned short* __restrict__ W2bf, const float* __restrict__ b2,
    const unsigned short* __restrict__ W3bf, const float* __restrict__ b3,
    const float* __restrict__ W4, const float* __restrict__ b4,
    const float* __restrict__ A_a, unsigned short* __restrict__ wTbf) {
  int blk = blockIdx.x;
  int b = blk >> 6;
  int u0 = (blk & 63) << 1;
  __shared__ char ycraw[8][4096];      // per-wave [32 v][64 m] bf16, swizzled
  __shared__ char w2all[65536];        // [256 m][128 k] bf16, swizzled
  __shared__ char w3all[32768];        // [64 j][256 k] bf16, swizzled
  int t = threadIdx.x;
  int lane = t & 63;
  int w = t >> 6;                      // 0..7
  int uw = u0 + (w >> 2);
  int lr = lane & 15;
  int lhi = lane >> 4;
  int v0w = (w & 3) * 32;
  int sw = (lr & 7) << 4;

  // ---- stage ALL weights once (96 KB; hides under X1 build) ----
  for (int s = w; s < 64; s += 8) {    // W2: [256 m][256 B rows]
    int o = s * 1024 + lane * 16;
    int row = o >> 8;
    int cbo = o & 255;
    const char* src = (const char*)W2bf + (size_t)row * 256 +
                      (cbo ^ ((row & 7) << 4));
    __builtin_amdgcn_global_load_lds(src, w2all + s * 1024, 16, 0, 0);
  }
  for (int s = w; s < 32; s += 8) {    // W3: [64 j][512 B rows]
    int o = s * 1024 + lane * 16;
    int row = o >> 9;
    int cbo = o & 511;
    const char* src = (const char*)W3bf + (size_t)row * 512 +
                      (cbo ^ ((row & 7) << 4));
    __builtin_amdgcn_global_load_lds(src, w3all + s * 1024, 16, 0, 0);
  }

  // ---- X1 fragments in registers: xf[ks][vg] = relu(fu+fv+b1) bf16 ----
  short8 xf[4][2];
  {
    const float* fu_base = fuv + ((size_t)(b * NC + uw)) * 256;
#pragma unroll
    for (int ks = 0; ks < 4; ks++) {
      int k0 = ks * 32 + lhi * 8;
      float4 fua = *(const float4*)(fu_base + k0);
      float4 fub4 = *(const float4*)(fu_base + k0 + 4);
      float4 b1a = *(const float4*)(b1 + k0);
      float4 b1b = *(const float4*)(b1 + k0 + 4);
#pragma unroll
      for (int vg = 0; vg < 2; vg++) {
        int v = v0w + vg * 16 + lr;
        const float* fvr = fuv + ((size_t)(b * NC + v)) * 256 + 128 + k0;
        float4 fva = *(const float4*)(fvr);
        float4 fvb = *(const float4*)(fvr + 4);
        float e[8];
        e[0] = fua.x + fva.x + b1a.x; e[1] = fua.y + fva.y + b1a.y;
        e[2] = fua.z + fva.z + b1a.z; e[3] = fua.w + fva.w + b1a.w;
        e[4] = fub4.x + fvb.x + b1b.x; e[5] = fub4.y + fvb.y + b1b.y;
        e[6] = fub4.z + fvb.z + b1b.z; e[7] = fub4.w + fvb.w + b1b.w;
        union { unsigned int pw[4]; short8 s8; } pk;
#pragma unroll
        for (int i2 = 0; i2 < 4; i2++) {
          float lo = e[2 * i2] > 0.f ? e[2 * i2] : 0.f;
          float hi = e[2 * i2 + 1] > 0.f ? e[2 * i2 + 1] : 0.f;
          pk.pw[i2] = (unsigned int)f2bf(lo) | ((unsigned int)f2bf(hi) << 16);
        }
        xf[ks][vg] = pk.s8;
      }
    }
  }
  __syncthreads();                     // full weight stage drained (overlapped)

  char* ycb = ycraw[w];
  f32x4 zacc[2][4];
#pragma unroll
  for (int q = 0; q < 2; q++)
#pragma unroll
    for (int n = 0; n < 4; n++) zacc[q][n] = (f32x4){0.f, 0.f, 0.f, 0.f};

  // ---- main loop: ZERO barriers, zero staging ----
  for (int c = 0; c < 4; c++) {
    int mc = c * 64;
    const char* w2base_c = w2all + mc * 256;   // rows mc..mc+63
    f32x4 yac[4][2];
#pragma unroll
    for (int mt = 0; mt < 4; mt++) {
      yac[mt][0] = (f32x4){0.f, 0.f, 0.f, 0.f};
      yac[mt][1] = (f32x4){0.f, 0.f, 0.f, 0.f};
    }
    __builtin_amdgcn_s_setprio(1);
#pragma unroll
    for (int ks = 0; ks < 4; ks++) {
#pragma unroll
      for (int mt = 0; mt < 4; mt++) {
        int wrow = mt * 16 + lr;
        short8 wv = *(const short8*)(
            w2base_c + wrow * 256 + ((ks * 64 + lhi * 16) ^ ((wrow & 7) << 4)));
        yac[mt][0] = __builtin_amdgcn_mfma_f32_16x16x32_bf16(wv, xf[ks][0], yac[mt][0], 0, 0, 0);
        yac[mt][1] = __builtin_amdgcn_mfma_f32_16x16x32_bf16(wv, xf[ks][1], yac[mt][1], 0, 0, 0);
      }
    }
    __builtin_amdgcn_s_setprio(0);
#pragma unroll
    for (int mt = 0; mt < 4; mt++) {
      float4 b2v = *(const float4*)(b2 + mc + mt * 16 + lhi * 4);
#pragma unroll
      for (int vg = 0; vg < 2; vg++) {
        int v = vg * 16 + lr;
        float e0 = yac[mt][vg][0] + b2v.x; e0 = e0 > 0.f ? e0 : 0.f;
        float e1 = yac[mt][vg][1] + b2v.y; e1 = e1 > 0.f ? e1 : 0.f;
        float e2 = yac[mt][vg][2] + b2v.z; e2 = e2 > 0.f ? e2 : 0.f;
        float e3 = yac[mt][vg][3] + b2v.w; e3 = e3 > 0.f ? e3 : 0.f;
        uint2 pw;
        pw.x = (unsigned)f2bf(e0) | ((unsigned)f2bf(e1) << 16);
        pw.y = (unsigned)f2bf(e2) | ((unsigned)f2bf(e3) << 16);
        int byte = (v * 128 + (mt * 16 + lhi * 4) * 2) ^ ((lr & 7) << 4);
        *(uint2*)(ycb + byte) = pw;
      }
    }
    __builtin_amdgcn_s_setprio(1);
#pragma unroll
    for (int ks2 = 0; ks2 < 2; ks2++) {
      int kb = ks2 * 32 + lhi * 8;
      short8 ya0 = *(const short8*)(ycb + ((lr * 128 + kb * 2) ^ sw));
      short8 ya1 = *(const short8*)(ycb + (((16 + lr) * 128 + kb * 2) ^ sw));
#pragma unroll
      for (int n = 0; n < 4; n++) {
        int jrow = 16 * n + lr;
        short8 w3v = *(const short8*)(
            w3all + jrow * 512 +
            ((mc * 2 + ks2 * 64 + lhi * 16) ^ ((jrow & 7) << 4)));
        zacc[0][n] = __builtin_amdgcn_mfma_f32_16x16x32_bf16(ya0, w3v, zacc[0][n], 0, 0, 0);
        zacc[1][n] = __builtin_amdgcn_mfma_f32_16x16x32_bf16(ya1, w3v, zacc[1][n], 0, 0, 0);
      }
    }
    __builtin_amdgcn_s_setprio(0);
  }

  // ---- layer3 bias/relu + layer4 dot + 16-lane butterfly + sigmoid ----
  float sp[2][4];
#pragma unroll
  for (int q = 0; q < 2; q++)
#pragma unroll
    for (int r = 0; r < 4; r++) sp[q][r] = 0.f;
#pragma unroll
  for (int n = 0; n < 4; n++) {
    int j = 16 * n + lr;
    float b3v = b3[j], w4v = W4[j];
#pragma unroll
    for (int q = 0; q < 2; q++)
#pragma unroll
      for (int r = 0; r < 4; r++) {
        float z = zacc[q][n][r] + b3v;
        z = z > 0.f ? z : 0.f;
        sp[q][r] += w4v * z;
      }
  }
#pragma unroll
  for (int mask = 1; mask <= 8; mask <<= 1)
#pragma unroll
    for (int q = 0; q < 2; q++)
#pragma unroll
      for (int r = 0; r < 4; r++)
        sp[q][r] += __shfl_xor(sp[q][r], mask, 64);
  float bb4 = b4[0];
  if (lr == 0) {
#pragma unroll
    for (int q = 0; q < 2; q++)
#pragma unroll
      for (int r = 0; r < 4; r++) {
        int v = v0w + 16 * q + lhi * 4 + r;
        float s = 1.f / (1.f + expf(-(sp[q][r] + bb4)));
        wTbf[((size_t)(b * NC + v)) * NC + uw] = f2bf(s * A_a[uw * NC + v]);
      }
  }
}

// ---------------------------------------------------------------------------
// D3: fused a/m einsums + projections + beta combine.  (verbatim R15-R18)
// ---------------------------------------------------------------------------
__global__ __launch_bounds__(128) void k_out_mfma(
    const float* __restrict__ h, const unsigned short* __restrict__ wTbf,
    const unsigned short* __restrict__ A_mTbf,
    const unsigned short* __restrict__ hbfT,
    const unsigned short* __restrict__ W_addbf,
    const unsigned short* __restrict__ W_modbf,
    const float* __restrict__ b_add, const float* __restrict__ b_mod,
    const float* __restrict__ beta1p, const float* __restrict__ beta2p,
    const float* __restrict__ beta3p, float* __restrict__ out) {
  int blk = blockIdx.x;
  int bt = blk >> 3;
  int v0 = (blk & 7) << 4;
  int b = bt / 20;
  __shared__ char apre_l[2048];
  __shared__ char mpre_l[2048];
  int t = threadIdx.x;
  int lane = t & 63;
  int w = t >> 6;
  int lr = lane & 15, lhi = lane >> 4;
  int nf0 = w * 2;

  f32x4 aacc[2], macc[2];
#pragma unroll
  for (int i = 0; i < 2; i++) {
    aacc[i] = (f32x4){0.f, 0.f, 0.f, 0.f};
    macc[i] = (f32x4){0.f, 0.f, 0.f, 0.f};
  }
  const unsigned short* wrow = wTbf + ((size_t)(b * NC + v0 + lr)) * NC + lhi * 8;
  const unsigned short* arow = A_mTbf + (size_t)(v0 + lr) * NC + lhi * 8;
  const unsigned short* hTrow = hbfT + (size_t)bt * 8192 + lhi * 8;
#pragma unroll
  for (int kb = 0; kb < 128; kb += 32) {
    short8 aw = *(const short8*)(wrow + kb);
    short8 am = *(const short8*)(arow + kb);
#pragma unroll
    for (int nfi = 0; nfi < 2; nfi++) {
      int nf = nf0 + nfi;
      short8 bv = *(const short8*)(hTrow + (size_t)(nf * 16 + lr) * NC + kb);
      aacc[nfi] = __builtin_amdgcn_mfma_f32_16x16x32_bf16(aw, bv, aacc[nfi], 0, 0, 0);
      macc[nfi] = __builtin_amdgcn_mfma_f32_16x16x32_bf16(am, bv, macc[nfi], 0, 0, 0);
    }
  }

  float hval[2][4];
  const float* hbase = h + (size_t)bt * 8192;
#pragma unroll
  for (int nfi = 0; nfi < 2; nfi++) {
    int d = (nf0 + nfi) * 16 + lr;
#pragma unroll
    for (int r = 0; r < 4; r++) {
      int vl = lhi * 4 + r;
      float hv = hbase[(size_t)(v0 + vl) * 64 + d];
      hval[nfi][r] = hv;
      int byte = (vl * 128 + d * 2) ^ ((vl & 7) << 4);
      *(unsigned short*)(apre_l + byte) = f2bf(aacc[nfi][r]);
      *(unsigned short*)(mpre_l + byte) = f2bf(macc[nfi][r] * hv);
    }
  }
  __syncthreads();

  f32x4 oa[2], om[2];
#pragma unroll
  for (int i = 0; i < 2; i++) {
    oa[i] = (f32x4){0.f, 0.f, 0.f, 0.f};
    om[i] = (f32x4){0.f, 0.f, 0.f, 0.f};
  }
  int sw = (lr & 7) << 4;
#pragma unroll
  for (int kb = 0; kb < 64; kb += 32) {
    int off0 = lr * 128 + kb * 2 + lhi * 16;
    short8 pa = *(const short8*)(apre_l + (off0 ^ sw));
    short8 pm = *(const short8*)(mpre_l + (off0 ^ sw));
#pragma unroll
    for (int nfi = 0; nfi < 2; nfi++) {
      int nf = nf0 + nfi;
      const unsigned short* wa = W_addbf + (size_t)(nf * 16 + lr) * 64 + kb + lhi * 8;
      const unsigned short* wm = W_modbf + (size_t)(nf * 16 + lr) * 64 + kb + lhi * 8;
      short8 wav = *(const short8*)wa;
      short8 wmv = *(const short8*)wm;
      oa[nfi] = __builtin_amdgcn_mfma_f32_16x16x32_bf16(pa, wav, oa[nfi], 0, 0, 0);
      om[nfi] = __builtin_amdgcn_mfma_f32_16x16x32_bf16(pm, wmv, om[nfi], 0, 0, 0);
    }
  }
  float bb1 = beta1p[0], bb2 = beta2p[0], bb3 = beta3p[0];
  float* obase = out + (size_t)bt * 8192 + (size_t)v0 * 64;
#pragma unroll
  for (int nfi = 0; nfi < 2; nfi++) {
    int d = (nf0 + nfi) * 16 + lr;
    float ba = b_add[d], bm = b_mod[d];
#pragma unroll
    for (int r = 0; r < 4; r++) {
      int vl = lhi * 4 + r;
      obase[(size_t)vl * 64 + d] =
          bb1 * hval[nfi][r] + bb2 * (oa[nfi][r] + ba) + bb3 * (om[nfi][r] + bm);
    }
  }
}

// ---------------------------------------------------------------------------
extern "C" void kernel_launch(void* const* d_in, const int* in_sizes, int n_in,
                              void* d_out, int out_size, void* d_ws, size_t ws_size,
                              hipStream_t stream) {
  const float* h     = (const float*)d_in[0];
  const float* W1    = (const float*)d_in[1];
  const float* b1    = (const float*)d_in[2];
  const float* W2    = (const float*)d_in[3];
  const float* b2    = (const float*)d_in[4];
  const float* W3    = (const float*)d_in[5];
  const float* b3    = (const float*)d_in[6];
  const float* W4    = (const float*)d_in[7];
  const float* b4    = (const float*)d_in[8];
  const float* A_a   = (const float*)d_in[9];
  const float* A_m   = (const float*)d_in[10];
  const float* W_add = (const float*)d_in[11];
  const float* b_add = (const float*)d_in[12];
  const float* W_mod = (const float*)d_in[13];
  const float* b_mod = (const float*)d_in[14];
  const float* beta1 = (const float*)d_in[15];
  const float* beta2 = (const float*)d_in[16];
  const float* beta3 = (const float*)d_in[17];
  float* out = (float*)d_out;

  char* ws = (char*)d_ws;
  float* fuv             = (float*)(ws);                         // 512 KB
  unsigned short* wTbf   = (unsigned short*)(ws + 512 * 1024);   // 128 KB
  unsigned short* A_mTbf = (unsigned short*)(ws + 640 * 1024);   // 32 KB
  unsigned short* W_addbf= (unsigned short*)(ws + 672 * 1024);   // 8 KB
  unsigned short* W_modbf= (unsigned short*)(ws + 680 * 1024);   // 8 KB
  unsigned short* W2bf   = (unsigned short*)(ws + 688 * 1024);   // 64 KB
  unsigned short* W3bf   = (unsigned short*)(ws + 752 * 1024);   // 32 KB
  unsigned short* hbfT   = (unsigned short*)(ws + 784 * 1024);   // 1280 KB

  k_front2<<<372, 128, 0, stream>>>(h, W1, W2, W3, A_m, W_add, W_mod,
                                    fuv, W2bf, W3bf, A_mTbf, W_addbf, W_modbf,
                                    hbfT);
  k_pair<<<256, 512, 0, stream>>>(fuv, b1, W2bf, b2, W3bf, b3, W4, b4, A_a, wTbf);
  k_out_mfma<<<640, 128, 0, stream>>>(h, wTbf, A_mTbf, hbfT, W_addbf, W_modbf,
                                      b_add, b_mod, beta1, beta2, beta3, out);
}